// Round 13
// baseline (1966.215 us; speedup 1.0000x reference)
//
#include <hip/hip_runtime.h>

#define NN 200000
#define NE 4000000
#define FIN 64
#define DIM 20
#define NGR 512
#define NCL 2
#define BN_EPS 1e-5f

#define BKT 391                 // dst buckets of 512 (dst>>9)
#define BNODE 512
#define NSL 8                   // src slices
#define SLCW 25000              // slice width (1.5625 MB of bf16 rows)
#define BINS (BKT * NSL)        // 3128
#define NCTR (8 * BINS)         // 25024 (xcd-split)
#define T2 32768
#define NT2 ((NE + T2 - 1) / T2)   // 123
#define SAC 21                  // LDS acc stride (bank-spread, gcd(21,32)=1)

typedef unsigned short ushort_t;

__device__ __forceinline__ ushort_t f2bf(float f) {   // RNE bf16
    unsigned u = __float_as_uint(f);
    unsigned r = (u + 0x7fffu + ((u >> 16) & 1u)) >> 16;
    return (ushort_t)r;
}

struct Row { uint4 a, b; uint2 c; };

__device__ __forceinline__ Row row_load(const ushort_t* __restrict__ yb, int s) {
    const uint4* rp = (const uint4*)(yb + (size_t)s * 32);
    Row r;
    r.a = rp[0];
    r.b = rp[1];
    r.c = ((const uint2*)rp)[4];
    return r;
}

__device__ __forceinline__ void row_unpack(const Row& r, float* v) {
    unsigned u[10] = {r.a.x, r.a.y, r.a.z, r.a.w, r.b.x, r.b.y, r.b.z, r.b.w, r.c.x, r.c.y};
    #pragma unroll
    for (int i = 0; i < 10; ++i) {
        v[2 * i]     = __uint_as_float(u[i] << 16);
        v[2 * i + 1] = __uint_as_float(u[i] & 0xffff0000u);
    }
}

__device__ __forceinline__ void edge_add(float* __restrict__ accb, int dl, const Row& r) {
    float* a = accb + dl * SAC;
    unsigned u[10] = {r.a.x, r.a.y, r.a.z, r.a.w, r.b.x, r.b.y, r.b.z, r.b.w, r.c.x, r.c.y};
    #pragma unroll
    for (int i = 0; i < 10; ++i) {
        atomicAdd(&a[2 * i],     __uint_as_float(u[i] << 16));
        atomicAdd(&a[2 * i + 1], __uint_as_float(u[i] & 0xffff0000u));
    }
}

// ---------------- pass 1: per-(xcd, bucket, slice) edge histogram ----------------
__global__ __launch_bounds__(256) void hist_kernel(const int* __restrict__ src, const int* __restrict__ dst,
                                                   int* __restrict__ ghist) {
    __shared__ int h[BINS];
    int t = threadIdx.x;
    for (int i = t; i < BINS; i += 256) h[i] = 0;
    __syncthreads();
    size_t base = (size_t)blockIdx.x * T2;
    for (int kk = 0; kk < 32; ++kk) {
        size_t e = base + (size_t)kk * 1024 + t * 4;
        if (e + 4 <= NE) {
            int4 d = *(const int4*)(dst + e);
            int4 s = *(const int4*)(src + e);
            atomicAdd(&h[(d.x >> 9) * NSL + s.x / SLCW], 1);
            atomicAdd(&h[(d.y >> 9) * NSL + s.y / SLCW], 1);
            atomicAdd(&h[(d.z >> 9) * NSL + s.z / SLCW], 1);
            atomicAdd(&h[(d.w >> 9) * NSL + s.w / SLCW], 1);
        } else {
            for (int j = 0; j < 4; ++j)
                if (e + j < NE) atomicAdd(&h[(dst[e + j] >> 9) * NSL + src[e + j] / SLCW], 1);
        }
    }
    __syncthreads();
    int r = blockIdx.x & 7;
    for (int i = t; i < BINS; i += 256)
        if (h[i]) atomicAdd(&ghist[r * BINS + i], h[i]);
}

// ---------------- pass 2: scan 25024 counters (logical idx = bin*8 + xcd) ----------------
__global__ __launch_bounds__(1024) void scan_small_kernel(const int* __restrict__ ghist,
                                                          int* __restrict__ bbase, int* __restrict__ bcur) {
    __shared__ int c[1024];
    int t = threadIdx.x;
    const int CH = (NCTR + 1023) / 1024;   // 25
    int beg = t * CH, end = min(beg + CH, NCTR);
    int s = 0;
    for (int idx = beg; idx < end; ++idx) s += ghist[(idx & 7) * BINS + (idx >> 3)];
    c[t] = s;
    __syncthreads();
    for (int off = 1; off < 1024; off <<= 1) {
        int u = (t >= off) ? c[t - off] : 0;
        __syncthreads();
        c[t] += u;
        __syncthreads();
    }
    int run = (t == 0) ? 0 : c[t - 1];
    for (int idx = beg; idx < end; ++idx) {
        int v = ghist[(idx & 7) * BINS + (idx >> 3)];
        bbase[idx] = run;
        bcur[(idx & 7) * BINS + (idx >> 3)] = run;
        run += v;
    }
    if (t == 1023) bbase[NCTR] = run;   // == NE
}

// ---------------- pass 3: multisplit scatter -> packed[] bucket-major, slice-ordered ----------------
__global__ __launch_bounds__(256) void p2_kernel(const int* __restrict__ src, const int* __restrict__ dst,
                                                 int* __restrict__ bcur, unsigned int* __restrict__ packed) {
    __shared__ int h[BINS], gb[BINS], lc[BINS];
    int t = threadIdx.x;
    for (int i = t; i < BINS; i += 256) { h[i] = 0; lc[i] = 0; }
    __syncthreads();
    size_t base = (size_t)blockIdx.x * T2;
    for (int kk = 0; kk < 32; ++kk) {
        size_t e = base + (size_t)kk * 1024 + t * 4;
        if (e + 4 <= NE) {
            int4 d = *(const int4*)(dst + e);
            int4 s = *(const int4*)(src + e);
            atomicAdd(&h[(d.x >> 9) * NSL + s.x / SLCW], 1);
            atomicAdd(&h[(d.y >> 9) * NSL + s.y / SLCW], 1);
            atomicAdd(&h[(d.z >> 9) * NSL + s.z / SLCW], 1);
            atomicAdd(&h[(d.w >> 9) * NSL + s.w / SLCW], 1);
        } else {
            for (int j = 0; j < 4; ++j)
                if (e + j < NE) atomicAdd(&h[(dst[e + j] >> 9) * NSL + src[e + j] / SLCW], 1);
        }
    }
    __syncthreads();
    int r = blockIdx.x & 7;
    for (int i = t; i < BINS; i += 256)
        gb[i] = h[i] ? atomicAdd(&bcur[r * BINS + i], h[i]) : 0;
    __syncthreads();
    for (int kk = 0; kk < 32; ++kk) {
        size_t e = base + (size_t)kk * 1024 + t * 4;
        if (e + 4 <= NE) {
            int4 d = *(const int4*)(dst + e);
            int4 s = *(const int4*)(src + e);
            int k, p;
            k = (d.x >> 9) * NSL + s.x / SLCW; p = gb[k] + atomicAdd(&lc[k], 1); packed[p] = ((unsigned)s.x << 9) | (unsigned)(d.x & 511);
            k = (d.y >> 9) * NSL + s.y / SLCW; p = gb[k] + atomicAdd(&lc[k], 1); packed[p] = ((unsigned)s.y << 9) | (unsigned)(d.y & 511);
            k = (d.z >> 9) * NSL + s.z / SLCW; p = gb[k] + atomicAdd(&lc[k], 1); packed[p] = ((unsigned)s.z << 9) | (unsigned)(d.z & 511);
            k = (d.w >> 9) * NSL + s.w / SLCW; p = gb[k] + atomicAdd(&lc[k], 1); packed[p] = ((unsigned)s.w << 9) | (unsigned)(d.w & 511);
        } else {
            for (int j = 0; j < 4; ++j) {
                if (e + j < NE) {
                    int dd = dst[e + j], ssv = src[e + j];
                    int k = (dd >> 9) * NSL + ssv / SLCW;
                    int p = gb[k] + atomicAdd(&lc[k], 1);
                    packed[p] = ((unsigned)ssv << 9) | (unsigned)(dd & 511);
                }
            }
        }
    }
}

// ---------------- degree count from packed -> dinv ----------------
__global__ __launch_bounds__(256) void cnt_kernel(const unsigned int* __restrict__ packed,
                                                  const int* __restrict__ bbase, float* __restrict__ dinv) {
    __shared__ int cnt[BNODE];
    int t = threadIdx.x;
    int b = blockIdx.x;
    for (int i = t; i < BNODE; i += 256) cnt[i] = 0;
    __syncthreads();
    int bb = bbase[b * NSL * 8], be = bbase[(b + 1) * NSL * 8];
    for (int i = bb + t; i < be; i += 256) atomicAdd(&cnt[packed[i] & 511], 1);
    __syncthreads();
    int n0 = b * BNODE;
    for (int i = t; i < BNODE; i += 256) {
        int n = n0 + i;
        if (n < NN) dinv[n] = rsqrtf(1.0f + (float)cnt[i]);
    }
}

// ---------------- layer0 linear: y_bf16 = (x @ W0) * dinv ----------------
__global__ __launch_bounds__(256) void lin0_kernel(const float* __restrict__ x, const float* __restrict__ W,
                                                   const float* __restrict__ dinv, ushort_t* __restrict__ yb) {
    __shared__ float sW[FIN * DIM];
    __shared__ float sX[64 * 65];
    __shared__ ushort_t sO[64 * 32];
    int tid = threadIdx.x;
    for (int i = tid; i < FIN * DIM; i += 256) sW[i] = W[i];
    int n0 = blockIdx.x * 64;
    #pragma unroll
    for (int k = 0; k < 16; ++k) {
        int idx = tid + k * 256;
        int row = idx >> 6, colf = idx & 63;
        sX[row * 65 + colf] = x[(size_t)(n0 + row) * FIN + colf];
    }
    __syncthreads();
    int nl = tid & 63, wq = tid >> 6;
    float acc[5] = {0.f, 0.f, 0.f, 0.f, 0.f};
    for (int f = 0; f < FIN; ++f) {
        float xv = sX[nl * 65 + f];
        #pragma unroll
        for (int k = 0; k < 5; ++k) acc[k] += xv * sW[f * DIM + wq + 4 * k];
    }
    float dv = dinv[n0 + nl];
    #pragma unroll
    for (int k = 0; k < 5; ++k) sO[nl * 32 + wq + 4 * k] = f2bf(acc[k] * dv);
    __syncthreads();
    if (tid < 192) {                                   // 64 rows x 3 uint4 (bytes 0..47)
        int row = tid / 3, part = tid - row * 3;
        ((uint4*)(yb + (size_t)(n0 + row) * 32))[part] = ((const uint4*)(sO + row * 32))[part];
    }
}

// ---------------- bucketed SpMM gather: LDS dst-accumulator, slice-ordered edge stream ----------------
__global__ __launch_bounds__(512) void gather_kernel(const ushort_t* __restrict__ yb,
                                                     const unsigned int* __restrict__ packed,
                                                     const int* __restrict__ bbase, const float* __restrict__ dinv,
                                                     const float* __restrict__ bia, float* __restrict__ agg,
                                                     float* __restrict__ stats) {
    __shared__ float acc[BNODE * SAC];   // 43008 B
    __shared__ float ls[2 * DIM];
    int t = threadIdx.x;
    int b = blockIdx.x;
    for (int i = t; i < BNODE * SAC; i += 512) acc[i] = 0.f;
    if (t < 2 * DIM) ls[t] = 0.f;
    __syncthreads();
    int i = bbase[b * NSL * 8] + t;
    int be = bbase[(b + 1) * NSL * 8];
    while (i + 1536 < be) {     // 4 edges in flight
        unsigned p0 = packed[i], p1 = packed[i + 512], p2 = packed[i + 1024], p3 = packed[i + 1536];
        Row r0 = row_load(yb, (int)(p0 >> 9));
        Row r1 = row_load(yb, (int)(p1 >> 9));
        Row r2 = row_load(yb, (int)(p2 >> 9));
        Row r3 = row_load(yb, (int)(p3 >> 9));
        __builtin_amdgcn_sched_barrier(0);
        edge_add(acc, (int)(p0 & 511), r0);
        edge_add(acc, (int)(p1 & 511), r1);
        edge_add(acc, (int)(p2 & 511), r2);
        edge_add(acc, (int)(p3 & 511), r3);
        i += 2048;
    }
    for (; i < be; i += 512) {
        unsigned p = packed[i];
        Row r = row_load(yb, (int)(p >> 9));
        edge_add(acc, (int)(p & 511), r);
    }
    __syncthreads();
    // finalize: one node per thread
    int n = b * BNODE + t;
    if (n < NN) {
        Row sr = row_load(yb, n);
        float sv[DIM];
        row_unpack(sr, sv);
        float di = dinv[n];
        const float* a = &acc[t * SAC];
        float res[DIM];
        #pragma unroll
        for (int j = 0; j < DIM; ++j) res[j] = (a[j] + sv[j]) * di + bia[j];
        float* ar = agg + (size_t)n * DIM;
        *(float4*)(ar + 0)  = make_float4(res[0], res[1], res[2], res[3]);
        *(float4*)(ar + 4)  = make_float4(res[4], res[5], res[6], res[7]);
        *(float4*)(ar + 8)  = make_float4(res[8], res[9], res[10], res[11]);
        *(float4*)(ar + 12) = make_float4(res[12], res[13], res[14], res[15]);
        *(float4*)(ar + 16) = make_float4(res[16], res[17], res[18], res[19]);
        #pragma unroll
        for (int jo = 0; jo < DIM; ++jo) {
            int j = (jo + t) % DIM;
            atomicAdd(&ls[j], res[j]);
            atomicAdd(&ls[DIM + j], res[j] * res[j]);
        }
    }
    __syncthreads();
    if (t < 2 * DIM) atomicAdd(&stats[t], ls[t]);
}

// ---------------- next linear (BN folded): y_bf16 = (relu(bn(agg)) @ W) * dinv ----------------
__global__ __launch_bounds__(256) void lin_next_kernel(const float* __restrict__ a, const float* __restrict__ stats,
                                                       const float* __restrict__ g, const float* __restrict__ beta,
                                                       const float* __restrict__ W, const float* __restrict__ dinv,
                                                       ushort_t* __restrict__ yb) {
    __shared__ float sW[DIM * DIM];
    __shared__ float sH[64 * 21];
    __shared__ float sS[2 * DIM];
    __shared__ ushort_t sO[64 * 32];
    int tid = threadIdx.x;
    for (int i = tid; i < DIM * DIM; i += 256) sW[i] = W[i];
    if (tid < DIM) {
        float mean = stats[tid] * (1.0f / NN);
        float var = stats[DIM + tid] * (1.0f / NN) - mean * mean;
        float sc = g[tid] * rsqrtf(var + BN_EPS);
        sS[tid] = sc;
        sS[DIM + tid] = beta[tid] - mean * sc;
    }
    __syncthreads();
    int n0 = blockIdx.x * 64;
    #pragma unroll
    for (int k = 0; k < 5; ++k) {
        int idx = tid + k * 256;
        int row = idx / DIM, colf = idx - row * DIM;
        float v = a[(size_t)(n0 + row) * DIM + colf];
        sH[row * 21 + colf] = fmaxf(v * sS[colf] + sS[DIM + colf], 0.0f);
    }
    __syncthreads();
    int nl = tid & 63, wq = tid >> 6;
    float acc[5] = {0.f, 0.f, 0.f, 0.f, 0.f};
    for (int f = 0; f < DIM; ++f) {
        float h = sH[nl * 21 + f];
        #pragma unroll
        for (int k = 0; k < 5; ++k) acc[k] += h * sW[f * DIM + wq + 4 * k];
    }
    float dv = dinv[n0 + nl];
    #pragma unroll
    for (int k = 0; k < 5; ++k) sO[nl * 32 + wq + 4 * k] = f2bf(acc[k] * dv);
    __syncthreads();
    if (tid < 192) {
        int row = tid / 3, part = tid - row * 3;
        ((uint4*)(yb + (size_t)(n0 + row) * 32))[part] = ((const uint4*)(sO + row * 32))[part];
    }
}

// ---------------- final (BN folded): relu(bn) -> emb + segment_max ----------------
__global__ __launch_bounds__(256) void final_kernel(const float* __restrict__ a, const float* __restrict__ stats,
                                                    const float* __restrict__ g, const float* __restrict__ beta,
                                                    const int* __restrict__ batch, float* __restrict__ emb,
                                                    unsigned int* __restrict__ ge) {
    __shared__ unsigned int lmax[8 * DIM];
    __shared__ float sS[2 * DIM];
    __shared__ int sg[2];
    int tid = threadIdx.x;
    if (tid < DIM) {
        float mean = stats[tid] * (1.0f / NN);
        float var = stats[DIM + tid] * (1.0f / NN) - mean * mean;
        float sc = g[tid] * rsqrtf(var + BN_EPS);
        sS[tid] = sc;
        sS[DIM + tid] = beta[tid] - mean * sc;
    }
    int n0 = blockIdx.x * 256;
    if (tid == 0) {
        int nlast = min(n0 + 255, NN - 1);
        sg[0] = batch[n0];
        sg[1] = batch[nlast] - batch[n0] + 1;
    }
    for (int i = tid; i < 8 * DIM; i += 256) lmax[i] = 0u;
    __syncthreads();
    int gmin = sg[0], gspan = sg[1];
    bool uselds = (gspan <= 8);
    int n = n0 + tid;
    if (n < NN) {
        int g2 = batch[n];
        float vals[DIM];
        const float4* ar = (const float4*)(a + (size_t)n * DIM);
        float4* er = (float4*)(emb + (size_t)n * DIM);
        #pragma unroll
        for (int c = 0; c < 5; ++c) {
            float4 v = ar[c];
            float r0 = fmaxf(v.x * sS[4*c+0] + sS[DIM + 4*c+0], 0.0f);
            float r1 = fmaxf(v.y * sS[4*c+1] + sS[DIM + 4*c+1], 0.0f);
            float r2 = fmaxf(v.z * sS[4*c+2] + sS[DIM + 4*c+2], 0.0f);
            float r3 = fmaxf(v.w * sS[4*c+3] + sS[DIM + 4*c+3], 0.0f);
            er[c] = make_float4(r0, r1, r2, r3);
            vals[4*c+0] = r0; vals[4*c+1] = r1; vals[4*c+2] = r2; vals[4*c+3] = r3;
        }
        if (uselds) {
            int base = (g2 - gmin) * DIM;
            #pragma unroll
            for (int jo = 0; jo < DIM; ++jo) {
                int j = (jo + tid) % DIM;
                atomicMax(&lmax[base + j], __float_as_uint(vals[j]));
            }
        } else {
            #pragma unroll
            for (int jo = 0; jo < DIM; ++jo) {
                int j = (jo + tid) % DIM;
                atomicMax(&ge[g2 * DIM + j], __float_as_uint(vals[j]));
            }
        }
    }
    __syncthreads();
    if (uselds) {
        for (int i = tid; i < gspan * DIM; i += 256) {
            unsigned int v = lmax[i];
            if (v) atomicMax(&ge[gmin * DIM + i], v);
        }
    }
}

// ---------------- fc head ----------------
__global__ __launch_bounds__(256) void fc_kernel(const float* __restrict__ ge, const float* __restrict__ fcW,
                                                 const float* __restrict__ fcb, float* __restrict__ out) {
    int gid = blockIdx.x * 256 + threadIdx.x;
    if (gid >= NGR * NCL) return;
    int g = gid >> 1, c = gid & 1;
    float acc = fcb[c];
    #pragma unroll
    for (int d = 0; d < DIM; ++d) acc += ge[g * DIM + d] * fcW[d * NCL + c];
    out[gid] = acc;
}

extern "C" void kernel_launch(void* const* d_in, const int* in_sizes, int n_in,
                              void* d_out, int out_size, void* d_ws, size_t ws_size,
                              hipStream_t stream) {
    const float* x     = (const float*)d_in[0];
    const int*   ei    = (const int*)d_in[1];
    const int*   src   = ei;
    const int*   dst   = ei + NE;
    const int*   batch = (const int*)d_in[2];
    const float* W0 = (const float*)d_in[3];  const float* b0 = (const float*)d_in[4];
    const float* g0 = (const float*)d_in[5];  const float* be0 = (const float*)d_in[6];
    const float* W1 = (const float*)d_in[7];  const float* b1 = (const float*)d_in[8];
    const float* g1 = (const float*)d_in[9];  const float* be1 = (const float*)d_in[10];
    const float* W2 = (const float*)d_in[11]; const float* b2 = (const float*)d_in[12];
    const float* g2 = (const float*)d_in[13]; const float* be2 = (const float*)d_in[14];
    const float* fcW = (const float*)d_in[15]; const float* fcb = (const float*)d_in[16];

    float* ws = (float*)d_ws;
    float* dinv     = ws;                               // NN
    float* stats    = ws + NN;                          // 192
    int*   ghist    = (int*)(ws + NN + 192);            // NCTR
    int*   bbase    = ghist + NCTR;                     // NCTR+1
    int*   bcur     = bbase + NCTR + 1;                 // NCTR
    float* agg      = ws + 275280;                      // NN*DIM fp32
    unsigned int* packed = (unsigned int*)(ws + 4275280);   // NE u32 (persists all layers)
    ushort_t* ybuf  = (ushort_t*)(ws + 8275280);        // NN rows x 64B

    float* emb    = (float*)d_out;                      // NN*DIM
    float* ge     = emb + (size_t)NN * DIM;             // NGR*DIM
    float* logits = ge + NGR * DIM;                     // NGR*NCL

    const int N_BLKS = (NN + 255) / 256;                // 782
    const int L_BLKS = NN / 64;                         // 3125

    hipMemsetAsync(ghist, 0, NCTR * sizeof(int), stream);
    hipMemsetAsync(stats, 0, 192 * sizeof(float), stream);
    hipMemsetAsync(ge, 0, NGR * DIM * sizeof(float), stream);

    // ---- CSR-free build: multisplit into (dst-bucket, src-slice)-ordered packed[] ----
    hist_kernel<<<NT2, 256, 0, stream>>>(src, dst, ghist);
    scan_small_kernel<<<1, 1024, 0, stream>>>(ghist, bbase, bcur);
    p2_kernel<<<NT2, 256, 0, stream>>>(src, dst, bcur, packed);
    cnt_kernel<<<BKT, 256, 0, stream>>>(packed, bbase, dinv);

    lin0_kernel<<<L_BLKS, 256, 0, stream>>>(x, W0, dinv, ybuf);

    gather_kernel<<<BKT, 512, 0, stream>>>(ybuf, packed, bbase, dinv, b0, agg, stats);
    lin_next_kernel<<<L_BLKS, 256, 0, stream>>>(agg, stats, g0, be0, W1, dinv, ybuf);

    gather_kernel<<<BKT, 512, 0, stream>>>(ybuf, packed, bbase, dinv, b1, agg, stats + 64);
    lin_next_kernel<<<L_BLKS, 256, 0, stream>>>(agg, stats + 64, g1, be1, W2, dinv, ybuf);

    gather_kernel<<<BKT, 512, 0, stream>>>(ybuf, packed, bbase, dinv, b2, agg, stats + 128);

    final_kernel<<<N_BLKS, 256, 0, stream>>>(agg, stats + 128, g2, be2, batch, emb, (unsigned int*)ge);
    fc_kernel<<<(NGR * NCL + 255) / 256, 256, 0, stream>>>(ge, fcW, fcb, logits);
}

// Round 14
// 842.102 us; speedup vs baseline: 2.3349x; 2.3349x over previous
//
#include <hip/hip_runtime.h>

#define NN 200000
#define NE 4000000
#define FIN 64
#define DIM 20
#define NGR 512
#define NCL 2
#define BN_EPS 1e-5f

#define BKT 391                 // dst buckets of 512 (dst>>9)
#define BNODE 512
#define NCTR (8 * BKT)          // 3128 (xcd-split bucket counters)
#define T2 32768
#define NT2 ((NE + T2 - 1) / T2)   // 123
#define NP 4                    // feature passes (5 feats each; subrow 16B, 3.2MB/pass)
#define G_BLKS 1563             // ceil(NN/128)

typedef unsigned short ushort_t;

__device__ __forceinline__ ushort_t f2bf(float f) {   // RNE bf16
    unsigned u = __float_as_uint(f);
    unsigned r = (u + 0x7fffu + ((u >> 16) & 1u)) >> 16;
    return (ushort_t)r;
}

// subrow = 8 bf16 slots, slots 0..4 hold feats 5p..5p+4 (5 = hi of .z, 6,7 unused)
__device__ __forceinline__ void sub_add(const uint4& r, float* acc) {
    acc[0] += __uint_as_float(r.x << 16);
    acc[1] += __uint_as_float(r.x & 0xffff0000u);
    acc[2] += __uint_as_float(r.y << 16);
    acc[3] += __uint_as_float(r.y & 0xffff0000u);
    acc[4] += __uint_as_float(r.z << 16);
}

// ---------------- pass 1: per-(xcd,bucket) edge histogram ----------------
__global__ __launch_bounds__(256) void hist_kernel(const int* __restrict__ dst, int* __restrict__ ghist) {
    __shared__ int h[BKT];
    int t = threadIdx.x;
    for (int i = t; i < BKT; i += 256) h[i] = 0;
    __syncthreads();
    size_t base = (size_t)blockIdx.x * T2;
    for (int kk = 0; kk < 32; ++kk) {
        size_t e = base + (size_t)kk * 1024 + t * 4;
        if (e + 4 <= NE) {
            int4 d = *(const int4*)(dst + e);
            atomicAdd(&h[d.x >> 9], 1);
            atomicAdd(&h[d.y >> 9], 1);
            atomicAdd(&h[d.z >> 9], 1);
            atomicAdd(&h[d.w >> 9], 1);
        } else {
            for (int j = 0; j < 4; ++j)
                if (e + j < NE) atomicAdd(&h[dst[e + j] >> 9], 1);
        }
    }
    __syncthreads();
    int r = blockIdx.x & 7;
    for (int i = t; i < BKT; i += 256)
        if (h[i]) atomicAdd(&ghist[r * BKT + i], h[i]);
}

// ---------------- pass 2: scan 3128 counters (logical idx = bucket*8 + xcd) ----------------
__global__ __launch_bounds__(1024) void scan_small_kernel(const int* __restrict__ ghist,
                                                          int* __restrict__ bbase, int* __restrict__ bcur) {
    __shared__ int c[1024];
    int t = threadIdx.x;
    int v[4];
    int sum = 0;
    #pragma unroll
    for (int j = 0; j < 4; ++j) {
        int idx = t * 4 + j;
        int x = 0;
        if (idx < NCTR) x = ghist[(idx & 7) * BKT + (idx >> 3)];
        v[j] = x; sum += x;
    }
    c[t] = sum;
    __syncthreads();
    for (int off = 1; off < 1024; off <<= 1) {
        int u = (t >= off) ? c[t - off] : 0;
        __syncthreads();
        c[t] += u;
        __syncthreads();
    }
    int run = (t == 0) ? 0 : c[t - 1];
    #pragma unroll
    for (int j = 0; j < 4; ++j) {
        int idx = t * 4 + j;
        if (idx < NCTR) {
            bbase[idx] = run;
            bcur[(idx & 7) * BKT + (idx >> 3)] = run;
        }
        run += v[j];
    }
    if (t == 1023) bbase[NCTR] = run;
}

// ---------------- pass 3: multisplit scatter ----------------
__global__ __launch_bounds__(256) void p2_kernel(const int* __restrict__ src, const int* __restrict__ dst,
                                                 int* __restrict__ bcur, unsigned int* __restrict__ packed) {
    __shared__ int h[BKT], gb[BKT], lc[BKT];
    int t = threadIdx.x;
    for (int i = t; i < BKT; i += 256) { h[i] = 0; lc[i] = 0; }
    __syncthreads();
    size_t base = (size_t)blockIdx.x * T2;
    for (int kk = 0; kk < 32; ++kk) {
        size_t e = base + (size_t)kk * 1024 + t * 4;
        if (e + 4 <= NE) {
            int4 d = *(const int4*)(dst + e);
            atomicAdd(&h[d.x >> 9], 1);
            atomicAdd(&h[d.y >> 9], 1);
            atomicAdd(&h[d.z >> 9], 1);
            atomicAdd(&h[d.w >> 9], 1);
        } else {
            for (int j = 0; j < 4; ++j)
                if (e + j < NE) atomicAdd(&h[dst[e + j] >> 9], 1);
        }
    }
    __syncthreads();
    int r = blockIdx.x & 7;
    for (int i = t; i < BKT; i += 256)
        gb[i] = h[i] ? atomicAdd(&bcur[r * BKT + i], h[i]) : 0;
    __syncthreads();
    for (int kk = 0; kk < 32; ++kk) {
        size_t e = base + (size_t)kk * 1024 + t * 4;
        if (e + 4 <= NE) {
            int4 d = *(const int4*)(dst + e);
            int4 s = *(const int4*)(src + e);
            int b, p;
            b = d.x >> 9; p = gb[b] + atomicAdd(&lc[b], 1); packed[p] = ((unsigned)s.x << 9) | (unsigned)(d.x & 511);
            b = d.y >> 9; p = gb[b] + atomicAdd(&lc[b], 1); packed[p] = ((unsigned)s.y << 9) | (unsigned)(d.y & 511);
            b = d.z >> 9; p = gb[b] + atomicAdd(&lc[b], 1); packed[p] = ((unsigned)s.z << 9) | (unsigned)(d.z & 511);
            b = d.w >> 9; p = gb[b] + atomicAdd(&lc[b], 1); packed[p] = ((unsigned)s.w << 9) | (unsigned)(d.w & 511);
        } else {
            for (int j = 0; j < 4; ++j) {
                if (e + j < NE) {
                    int dd = dst[e + j], ssv = src[e + j];
                    int b = dd >> 9;
                    int p = gb[b] + atomicAdd(&lc[b], 1);
                    packed[p] = ((unsigned)ssv << 9) | (unsigned)(dd & 511);
                }
            }
        }
    }
}

// ---------------- pass 4: per-bucket CSR finalize (sort by dst_low; rowend + dinv) ----------------
__global__ __launch_bounds__(256) void p3_kernel(const unsigned int* __restrict__ packed, const int* __restrict__ bbase,
                                                 int* __restrict__ col, int* __restrict__ rowend,
                                                 float* __restrict__ dinv) {
    __shared__ int lcnt[BNODE], lexc[BNODE], lcur[BNODE];
    __shared__ int tmp[256];
    int t = threadIdx.x;
    int b = blockIdx.x;
    for (int i = t; i < BNODE; i += 256) { lcnt[i] = 0; lcur[i] = 0; }
    __syncthreads();
    int beg = bbase[b * 8], end = bbase[(b + 1) * 8];
    for (int i = beg + t; i < end; i += 256) atomicAdd(&lcnt[packed[i] & 511], 1);
    __syncthreads();
    int c2 = lcnt[2 * t] + lcnt[2 * t + 1];
    tmp[t] = c2;
    __syncthreads();
    for (int off = 1; off < 256; off <<= 1) {
        int u = (t >= off) ? tmp[t - off] : 0;
        __syncthreads();
        tmp[t] += u;
        __syncthreads();
    }
    int ex = (t == 0) ? 0 : tmp[t - 1];
    lexc[2 * t] = ex;
    lexc[2 * t + 1] = ex + lcnt[2 * t];
    __syncthreads();
    for (int i = beg + t; i < end; i += 256) {
        unsigned int p = packed[i];
        int ld = p & 511;
        int pos = lexc[ld] + atomicAdd(&lcur[ld], 1);
        col[beg + pos] = (int)(p >> 9);
    }
    int n0 = b * BNODE;
    for (int i = t; i < BNODE; i += 256) {
        int n = n0 + i;
        if (n < NN) {
            int c = lcnt[i];
            rowend[n] = beg + lexc[i] + c;            // one past last edge of row n
            dinv[n] = rsqrtf(1.0f + (float)c);
        }
    }
}

// ---------------- layer0 linear: ysub[p][n] bf16 = ((x @ W0) * dinv) feature-split ----------------
__global__ __launch_bounds__(256) void lin0_kernel(const float* __restrict__ x, const float* __restrict__ W,
                                                   const float* __restrict__ dinv, ushort_t* __restrict__ ysub) {
    __shared__ float sW[FIN * DIM];
    __shared__ float sX[64 * 65];
    __shared__ ushort_t sO[64 * 32];
    int tid = threadIdx.x;
    for (int i = tid; i < FIN * DIM; i += 256) sW[i] = W[i];
    int n0 = blockIdx.x * 64;
    #pragma unroll
    for (int k = 0; k < 16; ++k) {
        int idx = tid + k * 256;
        int row = idx >> 6, colf = idx & 63;
        sX[row * 65 + colf] = x[(size_t)(n0 + row) * FIN + colf];
    }
    __syncthreads();
    int nl = tid & 63, wq = tid >> 6;
    float acc[5] = {0.f, 0.f, 0.f, 0.f, 0.f};
    for (int f = 0; f < FIN; ++f) {
        float xv = sX[nl * 65 + f];
        #pragma unroll
        for (int k = 0; k < 5; ++k) acc[k] += xv * sW[f * DIM + wq + 4 * k];
    }
    float dv = dinv[n0 + nl];
    #pragma unroll
    for (int k = 0; k < 5; ++k) {
        int f = wq + 4 * k;
        sO[nl * 32 + (f / 5) * 8 + (f % 5)] = f2bf(acc[k] * dv);   // pad slots 5..7 never read
    }
    __syncthreads();
    int p = tid >> 6, row = tid & 63;   // 256 threads = 4 regions x 64 rows
    *(uint4*)(ysub + ((size_t)p * NN + n0 + row) * 8) = *(const uint4*)(sO + row * 32 + p * 8);
}

// ---------------- per-feature-pass gather: 2 lanes/node, 4-deep pipeline, L2-resident subrows ----------------
__global__ __launch_bounds__(256) void gather_pass(const ushort_t* __restrict__ ysub, const int* __restrict__ col,
                                                   const int* __restrict__ rowend, const float* __restrict__ dinv,
                                                   const float* __restrict__ bia, float* __restrict__ a4,
                                                   float* __restrict__ stats, int p) {
    __shared__ float ls[10];
    int tid = threadIdx.x;
    if (tid < 10) ls[tid] = 0.f;
    __syncthreads();
    const ushort_t* yb = ysub + (size_t)p * NN * 8;
    int pr = tid >> 1, h = tid & 1;
    int n = blockIdx.x * 128 + pr;
    if (n < NN) {
        float acc[5] = {0.f, 0.f, 0.f, 0.f, 0.f};
        if (h == 0) sub_add(*(const uint4*)(yb + (size_t)n * 8), acc);   // self-loop
        int beg = (n == 0) ? 0 : rowend[n - 1];
        int end = rowend[n];
        int e = beg + h;
        int cnt = (end - e + 1) >> 1;
        while (cnt >= 4) {                       // 4 subrows in flight (16 VGPR)
            int s0 = __builtin_nontemporal_load(&col[e]);
            int s1 = __builtin_nontemporal_load(&col[e + 2]);
            int s2 = __builtin_nontemporal_load(&col[e + 4]);
            int s3 = __builtin_nontemporal_load(&col[e + 6]);
            uint4 r0 = *(const uint4*)(yb + (size_t)s0 * 8);
            uint4 r1 = *(const uint4*)(yb + (size_t)s1 * 8);
            uint4 r2 = *(const uint4*)(yb + (size_t)s2 * 8);
            uint4 r3 = *(const uint4*)(yb + (size_t)s3 * 8);
            __builtin_amdgcn_sched_barrier(0);
            sub_add(r0, acc);
            sub_add(r1, acc);
            sub_add(r2, acc);
            sub_add(r3, acc);
            e += 8; cnt -= 4;
        }
        if (cnt >= 2) {
            int s0 = __builtin_nontemporal_load(&col[e]);
            int s1 = __builtin_nontemporal_load(&col[e + 2]);
            uint4 r0 = *(const uint4*)(yb + (size_t)s0 * 8);
            uint4 r1 = *(const uint4*)(yb + (size_t)s1 * 8);
            __builtin_amdgcn_sched_barrier(0);
            sub_add(r0, acc);
            sub_add(r1, acc);
            e += 4; cnt -= 2;
        }
        if (cnt > 0) {
            int s0 = __builtin_nontemporal_load(&col[e]);
            sub_add(*(const uint4*)(yb + (size_t)s0 * 8), acc);
        }
        float di = dinv[n];
        float res[5];
        #pragma unroll
        for (int j = 0; j < 5; ++j) {
            acc[j] += __shfl_xor(acc[j], 1, 64);
            res[j] = acc[j] * di + bia[5 * p + j];
        }
        float* ar = a4 + ((size_t)p * NN + n) * 5;
        if (h == 0) { ar[0] = res[0]; ar[1] = res[1]; ar[2] = res[2]; }
        else        { ar[3] = res[3]; ar[4] = res[4]; }
        #pragma unroll
        for (int jo = 0; jo < 5; ++jo) {
            int j = (jo + pr) % 5;
            atomicAdd(&ls[j], 0.5f * res[j]);            // both lanes add -> halve
            atomicAdd(&ls[5 + j], 0.5f * res[j] * res[j]);
        }
    }
    __syncthreads();
    if (tid < 5)  atomicAdd(&stats[5 * p + tid], ls[tid]);
    else if (tid < 10) atomicAdd(&stats[DIM + 5 * p + tid - 5], ls[tid]);
}

// ---------------- next linear (BN folded): ysub = (relu(bn(a4)) @ W) * dinv ----------------
__global__ __launch_bounds__(256) void lin_next_kernel(const float* __restrict__ a4, const float* __restrict__ stats,
                                                       const float* __restrict__ g, const float* __restrict__ beta,
                                                       const float* __restrict__ W, const float* __restrict__ dinv,
                                                       ushort_t* __restrict__ ysub) {
    __shared__ float sW[DIM * DIM];
    __shared__ float sH[64 * 21];
    __shared__ float sS[2 * DIM];
    __shared__ ushort_t sO[64 * 32];
    int tid = threadIdx.x;
    for (int i = tid; i < DIM * DIM; i += 256) sW[i] = W[i];
    if (tid < DIM) {
        float mean = stats[tid] * (1.0f / NN);
        float var = stats[DIM + tid] * (1.0f / NN) - mean * mean;
        float sc = g[tid] * rsqrtf(var + BN_EPS);
        sS[tid] = sc;
        sS[DIM + tid] = beta[tid] - mean * sc;
    }
    __syncthreads();
    int n0 = blockIdx.x * 64;
    #pragma unroll
    for (int k = 0; k < 5; ++k) {
        int idx = tid + k * 256;
        int row = idx / DIM, cf = idx - row * DIM;
        float v = a4[((size_t)(cf / 5) * NN + n0 + row) * 5 + (cf % 5)];
        sH[row * 21 + cf] = fmaxf(v * sS[cf] + sS[DIM + cf], 0.0f);
    }
    __syncthreads();
    int nl = tid & 63, wq = tid >> 6;
    float acc[5] = {0.f, 0.f, 0.f, 0.f, 0.f};
    for (int f = 0; f < DIM; ++f) {
        float h = sH[nl * 21 + f];
        #pragma unroll
        for (int k = 0; k < 5; ++k) acc[k] += h * sW[f * DIM + wq + 4 * k];
    }
    float dv = dinv[n0 + nl];
    #pragma unroll
    for (int k = 0; k < 5; ++k) {
        int f = wq + 4 * k;
        sO[nl * 32 + (f / 5) * 8 + (f % 5)] = f2bf(acc[k] * dv);
    }
    __syncthreads();
    int p = tid >> 6, row = tid & 63;
    *(uint4*)(ysub + ((size_t)p * NN + n0 + row) * 8) = *(const uint4*)(sO + row * 32 + p * 8);
}

// ---------------- final (BN folded): relu(bn(a4)) -> emb + segment_max ----------------
__global__ __launch_bounds__(256) void final_kernel(const float* __restrict__ a4, const float* __restrict__ stats,
                                                    const float* __restrict__ g, const float* __restrict__ beta,
                                                    const int* __restrict__ batch, float* __restrict__ emb,
                                                    unsigned int* __restrict__ ge) {
    __shared__ unsigned int lmax[8 * DIM];
    __shared__ float sS[2 * DIM];
    __shared__ int sg[2];
    int tid = threadIdx.x;
    if (tid < DIM) {
        float mean = stats[tid] * (1.0f / NN);
        float var = stats[DIM + tid] * (1.0f / NN) - mean * mean;
        float sc = g[tid] * rsqrtf(var + BN_EPS);
        sS[tid] = sc;
        sS[DIM + tid] = beta[tid] - mean * sc;
    }
    int n0 = blockIdx.x * 256;
    if (tid == 0) {
        int nlast = min(n0 + 255, NN - 1);
        sg[0] = batch[n0];
        sg[1] = batch[nlast] - batch[n0] + 1;
    }
    for (int i = tid; i < 8 * DIM; i += 256) lmax[i] = 0u;
    __syncthreads();
    int gmin = sg[0], gspan = sg[1];
    bool uselds = (gspan <= 8);
    int n = n0 + tid;
    if (n < NN) {
        int g2 = batch[n];
        float vals[DIM];
        #pragma unroll
        for (int p = 0; p < NP; ++p) {
            const float* ar = a4 + ((size_t)p * NN + n) * 5;
            #pragma unroll
            for (int j = 0; j < 5; ++j) {
                int f = 5 * p + j;
                vals[f] = fmaxf(ar[j] * sS[f] + sS[DIM + f], 0.0f);
            }
        }
        float4* er = (float4*)(emb + (size_t)n * DIM);
        #pragma unroll
        for (int c = 0; c < 5; ++c)
            er[c] = make_float4(vals[4*c+0], vals[4*c+1], vals[4*c+2], vals[4*c+3]);
        if (uselds) {
            int base = (g2 - gmin) * DIM;
            #pragma unroll
            for (int jo = 0; jo < DIM; ++jo) {
                int j = (jo + tid) % DIM;
                atomicMax(&lmax[base + j], __float_as_uint(vals[j]));
            }
        } else {
            #pragma unroll
            for (int jo = 0; jo < DIM; ++jo) {
                int j = (jo + tid) % DIM;
                atomicMax(&ge[g2 * DIM + j], __float_as_uint(vals[j]));
            }
        }
    }
    __syncthreads();
    if (uselds) {
        for (int i = tid; i < gspan * DIM; i += 256) {
            unsigned int v = lmax[i];
            if (v) atomicMax(&ge[gmin * DIM + i], v);
        }
    }
}

// ---------------- fc head ----------------
__global__ __launch_bounds__(256) void fc_kernel(const float* __restrict__ ge, const float* __restrict__ fcW,
                                                 const float* __restrict__ fcb, float* __restrict__ out) {
    int gid = blockIdx.x * 256 + threadIdx.x;
    if (gid >= NGR * NCL) return;
    int g = gid >> 1, c = gid & 1;
    float acc = fcb[c];
    #pragma unroll
    for (int d = 0; d < DIM; ++d) acc += ge[g * DIM + d] * fcW[d * NCL + c];
    out[gid] = acc;
}

static void launch_layer_gather(const ushort_t* ysub, const int* col, const int* rowend, const float* dinv,
                                const float* b, float* a4, float* stats, hipStream_t stream) {
    for (int p = 0; p < NP; ++p)
        gather_pass<<<G_BLKS, 256, 0, stream>>>(ysub, col, rowend, dinv, b, a4, stats, p);
}

extern "C" void kernel_launch(void* const* d_in, const int* in_sizes, int n_in,
                              void* d_out, int out_size, void* d_ws, size_t ws_size,
                              hipStream_t stream) {
    const float* x     = (const float*)d_in[0];
    const int*   ei    = (const int*)d_in[1];
    const int*   src   = ei;
    const int*   dst   = ei + NE;
    const int*   batch = (const int*)d_in[2];
    const float* W0 = (const float*)d_in[3];  const float* b0 = (const float*)d_in[4];
    const float* g0 = (const float*)d_in[5];  const float* be0 = (const float*)d_in[6];
    const float* W1 = (const float*)d_in[7];  const float* b1 = (const float*)d_in[8];
    const float* g1 = (const float*)d_in[9];  const float* be1 = (const float*)d_in[10];
    const float* W2 = (const float*)d_in[11]; const float* b2 = (const float*)d_in[12];
    const float* g2 = (const float*)d_in[13]; const float* be2 = (const float*)d_in[14];
    const float* fcW = (const float*)d_in[15]; const float* fcb = (const float*)d_in[16];

    float* ws = (float*)d_ws;
    float* dinv     = ws;                               // NN
    int*   rowend   = (int*)(ws + NN);                  // NN
    float* stats    = ws + 2 * NN;                      // 192
    int*   ghist    = (int*)(stats + 192);              // NCTR
    int*   bbase    = ghist + NCTR;                     // NCTR+1
    int*   bcur     = bbase + NCTR + 1;                 // NCTR
    float* a4       = ws + 409600;                      // NP*NN*5 = 4,000,000 fp32; aliases packed[]
    unsigned int* packed = (unsigned int*)a4;           // NE u32 == NP*NN*5
    ushort_t* ysub  = (ushort_t*)(ws + 4409600);        // NP*NN*8 bf16 = 3.2M floats
    int*   col      = (int*)(ws + 7609600);             // NE ints

    float* emb    = (float*)d_out;                      // NN*DIM
    float* ge     = emb + (size_t)NN * DIM;             // NGR*DIM
    float* logits = ge + NGR * DIM;                     // NGR*NCL

    const int N_BLKS = (NN + 255) / 256;                // 782
    const int L_BLKS = NN / 64;                         // 3125

    hipMemsetAsync(ghist, 0, NCTR * sizeof(int), stream);
    hipMemsetAsync(stats, 0, 192 * sizeof(float), stream);
    hipMemsetAsync(ge, 0, NGR * DIM * sizeof(float), stream);

    // ---- CSR build: two-level multisplit, dst-sorted ----
    hist_kernel<<<NT2, 256, 0, stream>>>(dst, ghist);
    scan_small_kernel<<<1, 1024, 0, stream>>>(ghist, bbase, bcur);
    p2_kernel<<<NT2, 256, 0, stream>>>(src, dst, bcur, packed);
    p3_kernel<<<BKT, 256, 0, stream>>>(packed, bbase, col, rowend, dinv);

    lin0_kernel<<<L_BLKS, 256, 0, stream>>>(x, W0, dinv, ysub);   // packed dead after p3

    launch_layer_gather(ysub, col, rowend, dinv, b0, a4, stats, stream);
    lin_next_kernel<<<L_BLKS, 256, 0, stream>>>(a4, stats, g0, be0, W1, dinv, ysub);

    launch_layer_gather(ysub, col, rowend, dinv, b1, a4, stats + 64, stream);
    lin_next_kernel<<<L_BLKS, 256, 0, stream>>>(a4, stats + 64, g1, be1, W2, dinv, ysub);

    launch_layer_gather(ysub, col, rowend, dinv, b2, a4, stats + 128, stream);

    final_kernel<<<N_BLKS, 256, 0, stream>>>(a4, stats + 128, g2, be2, batch, emb, (unsigned int*)ge);
    fc_kernel<<<(NGR * NCL + 255) / 256, 256, 0, stream>>>(ge, fcW, fcb, logits);
}

// Round 15
// 463.646 us; speedup vs baseline: 4.2408x; 1.8163x over previous
//
#include <hip/hip_runtime.h>

#define NN 200000
#define NE 4000000
#define FIN 64
#define DIM 20
#define NGR 512
#define NCL 2
#define BN_EPS 1e-5f

#define BKT 391                 // buckets of 512 nodes (dst>>9)
#define BNODE 512
#define NCTR (8 * BKT)
#define T2 32768
#define NT2 ((NE + T2 - 1) / T2)   // 123
#define NSLC 4
#define SLCW 50000              // src-slice width

typedef unsigned short ushort_t;

__device__ __forceinline__ ushort_t f2bf(float f) {   // RNE bf16
    unsigned u = __float_as_uint(f);
    unsigned r = (u + 0x7fffu + ((u >> 16) & 1u)) >> 16;
    return (ushort_t)r;
}

struct Row { uint4 a, b; uint2 c; };

__device__ __forceinline__ Row row_load(const ushort_t* __restrict__ yb, int s) {
    const uint4* rp = (const uint4*)(yb + (size_t)s * 32);
    Row r;
    r.a = rp[0];
    r.b = rp[1];
    r.c = ((const uint2*)rp)[4];
    return r;
}

__device__ __forceinline__ void row_acc(const Row& r, float* acc) {
    unsigned u[10] = {r.a.x, r.a.y, r.a.z, r.a.w, r.b.x, r.b.y, r.b.z, r.b.w, r.c.x, r.c.y};
    #pragma unroll
    for (int i = 0; i < 10; ++i) {
        acc[2 * i]     += __uint_as_float(u[i] << 16);
        acc[2 * i + 1] += __uint_as_float(u[i] & 0xffff0000u);
    }
}

// ---------------- pass 1: per-(xcd,bucket) edge histogram ----------------
__global__ __launch_bounds__(256) void hist_kernel(const int* __restrict__ dst, int* __restrict__ ghist) {
    __shared__ int h[BKT];
    int t = threadIdx.x;
    for (int i = t; i < BKT; i += 256) h[i] = 0;
    __syncthreads();
    size_t base = (size_t)blockIdx.x * T2;
    for (int kk = 0; kk < 32; ++kk) {
        size_t e = base + (size_t)kk * 1024 + t * 4;
        if (e + 4 <= NE) {
            int4 d = *(const int4*)(dst + e);
            atomicAdd(&h[d.x >> 9], 1);
            atomicAdd(&h[d.y >> 9], 1);
            atomicAdd(&h[d.z >> 9], 1);
            atomicAdd(&h[d.w >> 9], 1);
        } else {
            for (int j = 0; j < 4; ++j)
                if (e + j < NE) atomicAdd(&h[dst[e + j] >> 9], 1);
        }
    }
    __syncthreads();
    int r = blockIdx.x & 7;
    for (int i = t; i < BKT; i += 256)
        if (h[i]) atomicAdd(&ghist[r * BKT + i], h[i]);
}

// ---------------- pass 2: scan 3128 counters ----------------
__global__ __launch_bounds__(1024) void scan_small_kernel(const int* __restrict__ ghist,
                                                          int* __restrict__ bbase, int* __restrict__ bcur) {
    __shared__ int c[1024];
    int t = threadIdx.x;
    int v[4];
    int sum = 0;
    #pragma unroll
    for (int j = 0; j < 4; ++j) {
        int idx = t * 4 + j;                 // logical order: idx = b*8 + r
        int x = 0;
        if (idx < NCTR) x = ghist[(idx & 7) * BKT + (idx >> 3)];
        v[j] = x; sum += x;
    }
    c[t] = sum;
    __syncthreads();
    for (int off = 1; off < 1024; off <<= 1) {
        int u = (t >= off) ? c[t - off] : 0;
        __syncthreads();
        c[t] += u;
        __syncthreads();
    }
    int run = (t == 0) ? 0 : c[t - 1];
    #pragma unroll
    for (int j = 0; j < 4; ++j) {
        int idx = t * 4 + j;
        if (idx < NCTR) {
            bbase[idx] = run;
            bcur[(idx & 7) * BKT + (idx >> 3)] = run;
        }
        run += v[j];
    }
    if (t == 1023) bbase[NCTR] = run;
}

// ---------------- pass 3: multisplit scatter ----------------
__global__ __launch_bounds__(256) void p2_kernel(const int* __restrict__ src, const int* __restrict__ dst,
                                                 int* __restrict__ bcur, unsigned int* __restrict__ packed) {
    __shared__ int h[BKT], gb[BKT], lc[BKT];
    int t = threadIdx.x;
    for (int i = t; i < BKT; i += 256) { h[i] = 0; lc[i] = 0; }
    __syncthreads();
    size_t base = (size_t)blockIdx.x * T2;
    for (int kk = 0; kk < 32; ++kk) {
        size_t e = base + (size_t)kk * 1024 + t * 4;
        if (e + 4 <= NE) {
            int4 d = *(const int4*)(dst + e);
            atomicAdd(&h[d.x >> 9], 1);
            atomicAdd(&h[d.y >> 9], 1);
            atomicAdd(&h[d.z >> 9], 1);
            atomicAdd(&h[d.w >> 9], 1);
        } else {
            for (int j = 0; j < 4; ++j)
                if (e + j < NE) atomicAdd(&h[dst[e + j] >> 9], 1);
        }
    }
    __syncthreads();
    int r = blockIdx.x & 7;
    for (int i = t; i < BKT; i += 256)
        gb[i] = h[i] ? atomicAdd(&bcur[r * BKT + i], h[i]) : 0;
    __syncthreads();
    for (int kk = 0; kk < 32; ++kk) {
        size_t e = base + (size_t)kk * 1024 + t * 4;
        if (e + 4 <= NE) {
            int4 d = *(const int4*)(dst + e);
            int4 s = *(const int4*)(src + e);
            int b, p;
            b = d.x >> 9; p = gb[b] + atomicAdd(&lc[b], 1); packed[p] = ((unsigned)s.x << 9) | (unsigned)(d.x & 511);
            b = d.y >> 9; p = gb[b] + atomicAdd(&lc[b], 1); packed[p] = ((unsigned)s.y << 9) | (unsigned)(d.y & 511);
            b = d.z >> 9; p = gb[b] + atomicAdd(&lc[b], 1); packed[p] = ((unsigned)s.z << 9) | (unsigned)(d.z & 511);
            b = d.w >> 9; p = gb[b] + atomicAdd(&lc[b], 1); packed[p] = ((unsigned)s.w << 9) | (unsigned)(d.w & 511);
        } else {
            for (int j = 0; j < 4; ++j) {
                if (e + j < NE) {
                    int dd = dst[e + j], ssv = src[e + j];
                    int b = dd >> 9;
                    int p = gb[b] + atomicAdd(&lc[b], 1);
                    packed[p] = ((unsigned)ssv << 9) | (unsigned)(dd & 511);
                }
            }
        }
    }
}

// ---------------- pass 4: per-bucket CSR finalize, segments ordered by (dst_low, src_slice) ----------------
__global__ __launch_bounds__(256) void p3_kernel(const unsigned int* __restrict__ packed, const int* __restrict__ bbase,
                                                 int* __restrict__ col, int* __restrict__ rowstart,
                                                 float* __restrict__ dinv) {
    __shared__ int lcnt[BNODE * NSLC], lexc[BNODE * NSLC], lcur[BNODE * NSLC];
    __shared__ int tmp[256];
    int t = threadIdx.x;
    int b = blockIdx.x;
    for (int i = t; i < BNODE * NSLC; i += 256) { lcnt[i] = 0; lcur[i] = 0; }
    __syncthreads();
    int beg = bbase[b * 8], end = bbase[(b + 1) * 8];
    for (int i = beg + t; i < end; i += 256) {
        unsigned p = packed[i];
        int k = (int)(p & 511) * NSLC + (int)(p >> 9) / SLCW;
        atomicAdd(&lcnt[k], 1);
    }
    __syncthreads();
    int myv[8];
    int ssum = 0;
    #pragma unroll
    for (int j = 0; j < 8; ++j) { myv[j] = lcnt[t * 8 + j]; ssum += myv[j]; }
    tmp[t] = ssum;
    __syncthreads();
    for (int off = 1; off < 256; off <<= 1) {
        int u = (t >= off) ? tmp[t - off] : 0;
        __syncthreads();
        tmp[t] += u;
        __syncthreads();
    }
    int run = (t == 0) ? 0 : tmp[t - 1];
    #pragma unroll
    for (int j = 0; j < 8; ++j) { lexc[t * 8 + j] = run; run += myv[j]; }
    __syncthreads();
    for (int i = beg + t; i < end; i += 256) {
        unsigned p = packed[i];
        int sv = (int)(p >> 9);
        int k = (int)(p & 511) * NSLC + sv / SLCW;
        int pos = lexc[k] + atomicAdd(&lcur[k], 1);
        col[beg + pos] = sv;
    }
    __syncthreads();
    int n0 = b * BNODE;
    for (int i = t; i < BNODE; i += 256) {
        int n = n0 + i;
        if (n < NN) {
            int st = lexc[i * NSLC];
            int en = (i == BNODE - 1) ? (end - beg) : lexc[(i + 1) * NSLC];
            rowstart[n] = beg + en;                       // exclusive row end
            dinv[n] = rsqrtf(1.0f + (float)(en - st));
        }
    }
}

// ---------------- layer0 linear: y_bf16 = (x @ W0) * dinv ----------------
__global__ __launch_bounds__(256) void lin0_kernel(const float* __restrict__ x, const float* __restrict__ W,
                                                   const float* __restrict__ dinv, ushort_t* __restrict__ yb) {
    __shared__ float sW[FIN * DIM];
    __shared__ float sX[64 * 65];
    __shared__ ushort_t sO[64 * 32];
    int tid = threadIdx.x;
    for (int i = tid; i < FIN * DIM; i += 256) sW[i] = W[i];
    int n0 = blockIdx.x * 64;
    #pragma unroll
    for (int k = 0; k < 16; ++k) {
        int idx = tid + k * 256;
        int row = idx >> 6, colf = idx & 63;
        sX[row * 65 + colf] = x[(size_t)(n0 + row) * FIN + colf];
    }
    __syncthreads();
    int nl = tid & 63, wq = tid >> 6;
    float acc[5] = {0.f, 0.f, 0.f, 0.f, 0.f};
    for (int f = 0; f < FIN; ++f) {
        float xv = sX[nl * 65 + f];
        #pragma unroll
        for (int k = 0; k < 5; ++k) acc[k] += xv * sW[f * DIM + wq + 4 * k];
    }
    float dv = dinv[n0 + nl];
    #pragma unroll
    for (int k = 0; k < 5; ++k) sO[nl * 32 + wq + 4 * k] = f2bf(acc[k] * dv);
    __syncthreads();
    if (tid < 192) {                                   // 64 rows x 3 uint4 (bytes 0..47)
        int row = tid / 3, part = tid - row * 3;
        ((uint4*)(yb + (size_t)(n0 + row) * 32))[part] = ((const uint4*)(sO + row * 32))[part];
    }
}

// ---------------- CSR gather: 4 lanes/node, 4-row pipeline, high-VGPR for true MLP ----------------
__global__ __launch_bounds__(256, 2) void gather_kernel(const ushort_t* __restrict__ yb, const int* __restrict__ col,
                                                        const int* __restrict__ rowstart, const float* __restrict__ dinv,
                                                        const float* __restrict__ bia, float* __restrict__ agg,
                                                        float* __restrict__ stats) {
    __shared__ float ls[2 * DIM];
    int tid = threadIdx.x;
    if (tid < 2 * DIM) ls[tid] = 0.f;
    __syncthreads();
    int n = blockIdx.x * 64 + (tid >> 2);
    int q = tid & 3;
    float acc[DIM];
    if (n < NN) {
        #pragma unroll
        for (int j = 0; j < DIM; ++j) acc[j] = 0.f;
        if (q == 0) row_acc(row_load(yb, n), acc);               // self-loop
        int beg = (n == 0) ? 0 : rowstart[n - 1];
        int end = rowstart[n];
        int e = beg + q;
        int cnt = (end - e + 3) >> 2;                            // this lane's edges: e, e+4, ...
        if (end <= e) cnt = 0;
        while (cnt >= 4) {                                       // 4 rows (12 loads) in flight
            int s0 = col[e], s1 = col[e + 4], s2 = col[e + 8], s3 = col[e + 12];
            Row r0 = row_load(yb, s0);
            Row r1 = row_load(yb, s1);
            Row r2 = row_load(yb, s2);
            Row r3 = row_load(yb, s3);
            __builtin_amdgcn_sched_barrier(0);
            row_acc(r0, acc);
            row_acc(r1, acc);
            row_acc(r2, acc);
            row_acc(r3, acc);
            e += 16; cnt -= 4;
        }
        if (cnt >= 2) {
            int s0 = col[e], s1 = col[e + 4];
            Row r0 = row_load(yb, s0);
            Row r1 = row_load(yb, s1);
            __builtin_amdgcn_sched_barrier(0);
            row_acc(r0, acc);
            row_acc(r1, acc);
            e += 8; cnt -= 2;
        }
        if (cnt > 0) row_acc(row_load(yb, col[e]), acc);
        float di = dinv[n];
        #pragma unroll
        for (int j = 0; j < DIM; ++j) {
            acc[j] += __shfl_xor(acc[j], 1, 64);
            acc[j] += __shfl_xor(acc[j], 2, 64);
            acc[j] = acc[j] * di + bia[j];
        }
        float* ar = agg + (size_t)n * DIM;
        if (q < 3) {
            *(float4*)(ar + 4 * q) = make_float4(acc[4*q], acc[4*q+1], acc[4*q+2], acc[4*q+3]);
        } else {
            *(float4*)(ar + 12) = make_float4(acc[12], acc[13], acc[14], acc[15]);
            *(float4*)(ar + 16) = make_float4(acc[16], acc[17], acc[18], acc[19]);
        }
        int pr = tid >> 2;
        #pragma unroll
        for (int jo = 0; jo < 5; ++jo) {
            int j = 5 * q + ((jo + pr) % 5);
            atomicAdd(&ls[j], acc[j]);
            atomicAdd(&ls[DIM + j], acc[j] * acc[j]);
        }
    }
    __syncthreads();
    if (tid < 2 * DIM) atomicAdd(&stats[tid], ls[tid]);
}

// ---------------- next linear (BN folded): y_bf16 = (relu(bn(agg)) @ W) * dinv ----------------
__global__ __launch_bounds__(256) void lin_next_kernel(const float* __restrict__ a, const float* __restrict__ stats,
                                                       const float* __restrict__ g, const float* __restrict__ beta,
                                                       const float* __restrict__ W, const float* __restrict__ dinv,
                                                       ushort_t* __restrict__ yb) {
    __shared__ float sW[DIM * DIM];
    __shared__ float sH[64 * 21];
    __shared__ float sS[2 * DIM];
    __shared__ ushort_t sO[64 * 32];
    int tid = threadIdx.x;
    for (int i = tid; i < DIM * DIM; i += 256) sW[i] = W[i];
    if (tid < DIM) {
        float mean = stats[tid] * (1.0f / NN);
        float var = stats[DIM + tid] * (1.0f / NN) - mean * mean;
        float sc = g[tid] * rsqrtf(var + BN_EPS);
        sS[tid] = sc;
        sS[DIM + tid] = beta[tid] - mean * sc;
    }
    __syncthreads();
    int n0 = blockIdx.x * 64;
    #pragma unroll
    for (int k = 0; k < 5; ++k) {
        int idx = tid + k * 256;
        int row = idx / DIM, colf = idx - row * DIM;
        float v = a[(size_t)(n0 + row) * DIM + colf];
        sH[row * 21 + colf] = fmaxf(v * sS[colf] + sS[DIM + colf], 0.0f);
    }
    __syncthreads();
    int nl = tid & 63, wq = tid >> 6;
    float acc[5] = {0.f, 0.f, 0.f, 0.f, 0.f};
    for (int f = 0; f < DIM; ++f) {
        float h = sH[nl * 21 + f];
        #pragma unroll
        for (int k = 0; k < 5; ++k) acc[k] += h * sW[f * DIM + wq + 4 * k];
    }
    float dv = dinv[n0 + nl];
    #pragma unroll
    for (int k = 0; k < 5; ++k) sO[nl * 32 + wq + 4 * k] = f2bf(acc[k] * dv);
    __syncthreads();
    if (tid < 192) {
        int row = tid / 3, part = tid - row * 3;
        ((uint4*)(yb + (size_t)(n0 + row) * 32))[part] = ((const uint4*)(sO + row * 32))[part];
    }
}

// ---------------- final (BN folded): relu(bn) -> emb + segment_max ----------------
__global__ __launch_bounds__(256) void final_kernel(const float* __restrict__ a, const float* __restrict__ stats,
                                                    const float* __restrict__ g, const float* __restrict__ beta,
                                                    const int* __restrict__ batch, float* __restrict__ emb,
                                                    unsigned int* __restrict__ ge) {
    __shared__ unsigned int lmax[8 * DIM];
    __shared__ float sS[2 * DIM];
    __shared__ int sg[2];
    int tid = threadIdx.x;
    if (tid < DIM) {
        float mean = stats[tid] * (1.0f / NN);
        float var = stats[DIM + tid] * (1.0f / NN) - mean * mean;
        float sc = g[tid] * rsqrtf(var + BN_EPS);
        sS[tid] = sc;
        sS[DIM + tid] = beta[tid] - mean * sc;
    }
    int n0 = blockIdx.x * 256;
    if (tid == 0) {
        int nlast = min(n0 + 255, NN - 1);
        sg[0] = batch[n0];
        sg[1] = batch[nlast] - batch[n0] + 1;
    }
    for (int i = tid; i < 8 * DIM; i += 256) lmax[i] = 0u;
    __syncthreads();
    int gmin = sg[0], gspan = sg[1];
    bool uselds = (gspan <= 8);
    int n = n0 + tid;
    if (n < NN) {
        int g2 = batch[n];
        float vals[DIM];
        const float4* ar = (const float4*)(a + (size_t)n * DIM);
        float4* er = (float4*)(emb + (size_t)n * DIM);
        #pragma unroll
        for (int c = 0; c < 5; ++c) {
            float4 v = ar[c];
            float r0 = fmaxf(v.x * sS[4*c+0] + sS[DIM + 4*c+0], 0.0f);
            float r1 = fmaxf(v.y * sS[4*c+1] + sS[DIM + 4*c+1], 0.0f);
            float r2 = fmaxf(v.z * sS[4*c+2] + sS[DIM + 4*c+2], 0.0f);
            float r3 = fmaxf(v.w * sS[4*c+3] + sS[DIM + 4*c+3], 0.0f);
            er[c] = make_float4(r0, r1, r2, r3);
            vals[4*c+0] = r0; vals[4*c+1] = r1; vals[4*c+2] = r2; vals[4*c+3] = r3;
        }
        if (uselds) {
            int base = (g2 - gmin) * DIM;
            #pragma unroll
            for (int jo = 0; jo < DIM; ++jo) {
                int j = (jo + tid) % DIM;
                atomicMax(&lmax[base + j], __float_as_uint(vals[j]));
            }
        } else {
            #pragma unroll
            for (int jo = 0; jo < DIM; ++jo) {
                int j = (jo + tid) % DIM;
                atomicMax(&ge[g2 * DIM + j], __float_as_uint(vals[j]));
            }
        }
    }
    __syncthreads();
    if (uselds) {
        for (int i = tid; i < gspan * DIM; i += 256) {
            unsigned int v = lmax[i];
            if (v) atomicMax(&ge[gmin * DIM + i], v);
        }
    }
}

// ---------------- fc head ----------------
__global__ __launch_bounds__(256) void fc_kernel(const float* __restrict__ ge, const float* __restrict__ fcW,
                                                 const float* __restrict__ fcb, float* __restrict__ out) {
    int gid = blockIdx.x * 256 + threadIdx.x;
    if (gid >= NGR * NCL) return;
    int g = gid >> 1, c = gid & 1;
    float acc = fcb[c];
    #pragma unroll
    for (int d = 0; d < DIM; ++d) acc += ge[g * DIM + d] * fcW[d * NCL + c];
    out[gid] = acc;
}

extern "C" void kernel_launch(void* const* d_in, const int* in_sizes, int n_in,
                              void* d_out, int out_size, void* d_ws, size_t ws_size,
                              hipStream_t stream) {
    const float* x     = (const float*)d_in[0];
    const int*   ei    = (const int*)d_in[1];
    const int*   src   = ei;
    const int*   dst   = ei + NE;
    const int*   batch = (const int*)d_in[2];
    const float* W0 = (const float*)d_in[3];  const float* b0 = (const float*)d_in[4];
    const float* g0 = (const float*)d_in[5];  const float* be0 = (const float*)d_in[6];
    const float* W1 = (const float*)d_in[7];  const float* b1 = (const float*)d_in[8];
    const float* g1 = (const float*)d_in[9];  const float* be1 = (const float*)d_in[10];
    const float* W2 = (const float*)d_in[11]; const float* b2 = (const float*)d_in[12];
    const float* g2 = (const float*)d_in[13]; const float* be2 = (const float*)d_in[14];
    const float* fcW = (const float*)d_in[15]; const float* fcb = (const float*)d_in[16];

    float* ws = (float*)d_ws;
    float* dinv     = ws;                               // NN
    int*   rowstart = (int*)(ws + NN);                  // NN (exclusive row ends)
    float* stats    = ws + 2 * NN;                      // 192
    int*   ghist    = (int*)(stats + 192);              // NCTR
    int*   bbase    = ghist + NCTR;                     // NCTR+1
    int*   bcur     = bbase + NCTR + 1;                 // NCTR
    float* agg      = ws + 409700;                      // NN*DIM fp32; aliases packed[]
    unsigned int* packed = (unsigned int*)agg;          // NE u32 == NN*DIM
    ushort_t* ybuf  = (ushort_t*)(ws + 4409712);        // NN rows x 64B
    int*   col      = (int*)(ws + 4409712 + (size_t)NN * 16);   // NE ints

    float* emb    = (float*)d_out;                      // NN*DIM
    float* ge     = emb + (size_t)NN * DIM;             // NGR*DIM
    float* logits = ge + NGR * DIM;                     // NGR*NCL

    const int N_BLKS = (NN + 255) / 256;                // 782
    const int L_BLKS = NN / 64;                         // 3125 (linears + gather)

    hipMemsetAsync(ghist, 0, NCTR * sizeof(int), stream);
    hipMemsetAsync(stats, 0, 192 * sizeof(float), stream);
    hipMemsetAsync(ge, 0, NGR * DIM * sizeof(float), stream);

    // ---- CSR build: two-level multisplit, (dst_low, src_slice)-sorted segments ----
    hist_kernel<<<NT2, 256, 0, stream>>>(dst, ghist);
    scan_small_kernel<<<1, 1024, 0, stream>>>(ghist, bbase, bcur);
    p2_kernel<<<NT2, 256, 0, stream>>>(src, dst, bcur, packed);
    p3_kernel<<<BKT, 256, 0, stream>>>(packed, bbase, col, rowstart, dinv);

    lin0_kernel<<<L_BLKS, 256, 0, stream>>>(x, W0, dinv, ybuf);   // packed dead after p3

    gather_kernel<<<L_BLKS, 256, 0, stream>>>(ybuf, col, rowstart, dinv, b0, agg, stats);
    lin_next_kernel<<<L_BLKS, 256, 0, stream>>>(agg, stats, g0, be0, W1, dinv, ybuf);

    gather_kernel<<<L_BLKS, 256, 0, stream>>>(ybuf, col, rowstart, dinv, b1, agg, stats + 64);
    lin_next_kernel<<<L_BLKS, 256, 0, stream>>>(agg, stats + 64, g1, be1, W2, dinv, ybuf);

    gather_kernel<<<L_BLKS, 256, 0, stream>>>(ybuf, col, rowstart, dinv, b2, agg, stats + 128);

    final_kernel<<<N_BLKS, 256, 0, stream>>>(agg, stats + 128, g2, be2, batch, emb, (unsigned int*)ge);
    fc_kernel<<<(NGR * NCL + 255) / 256, 256, 0, stream>>>(ge, fcW, fcb, logits);
}

// Round 16
// 423.051 us; speedup vs baseline: 4.6477x; 1.0960x over previous
//
#include <hip/hip_runtime.h>

#define NN 200000
#define NE 4000000
#define FIN 64
#define DIM 20
#define NGR 512
#define NCL 2
#define BN_EPS 1e-5f

#define BKT 391                 // buckets of 512 nodes (dst>>9)
#define BNODE 512
#define NCTR (8 * BKT)
#define T2 32768
#define NT2 ((NE + T2 - 1) / T2)   // 123
#define NSLC 4
#define SLCW 50000              // src-slice width

typedef unsigned short ushort_t;

__device__ __forceinline__ ushort_t f2bf(float f) {   // RNE bf16
    unsigned u = __float_as_uint(f);
    unsigned r = (u + 0x7fffu + ((u >> 16) & 1u)) >> 16;
    return (ushort_t)r;
}

struct Row { uint4 a, b; uint2 c; };

__device__ __forceinline__ Row row_load(const ushort_t* __restrict__ yb, int s) {
    const uint4* rp = (const uint4*)(yb + (size_t)s * 32);
    Row r;
    r.a = rp[0];
    r.b = rp[1];
    r.c = ((const uint2*)rp)[4];
    return r;
}

__device__ __forceinline__ void row_acc(const Row& r, float* acc) {
    unsigned u[10] = {r.a.x, r.a.y, r.a.z, r.a.w, r.b.x, r.b.y, r.b.z, r.b.w, r.c.x, r.c.y};
    #pragma unroll
    for (int i = 0; i < 10; ++i) {
        acc[2 * i]     += __uint_as_float(u[i] << 16);
        acc[2 * i + 1] += __uint_as_float(u[i] & 0xffff0000u);
    }
}

// asm row load: 3 opaque loads -> results pinned in VGPRs until consumed
__device__ __forceinline__ void row_load_asm(const ushort_t* yb, int s, uint4& ra, uint4& rb, uint2& rc) {
    unsigned long long ap = (unsigned long long)(yb + (size_t)s * 32);
    asm volatile("global_load_dwordx4 %0, %1, off"           : "=v"(ra) : "v"(ap));
    asm volatile("global_load_dwordx4 %0, %1, off offset:16" : "=v"(rb) : "v"(ap));
    asm volatile("global_load_dwordx2 %0, %1, off offset:32" : "=v"(rc) : "v"(ap));
}

__device__ __forceinline__ void acc10(const uint4& a, const uint4& b, const uint2& c, float* acc) {
    unsigned u[10] = {a.x, a.y, a.z, a.w, b.x, b.y, b.z, b.w, c.x, c.y};
    #pragma unroll
    for (int i = 0; i < 10; ++i) {
        acc[2 * i]     += __uint_as_float(u[i] << 16);
        acc[2 * i + 1] += __uint_as_float(u[i] & 0xffff0000u);
    }
}

// ---------------- pass 1: per-(xcd,bucket) edge histogram ----------------
__global__ __launch_bounds__(256) void hist_kernel(const int* __restrict__ dst, int* __restrict__ ghist) {
    __shared__ int h[BKT];
    int t = threadIdx.x;
    for (int i = t; i < BKT; i += 256) h[i] = 0;
    __syncthreads();
    size_t base = (size_t)blockIdx.x * T2;
    for (int kk = 0; kk < 32; ++kk) {
        size_t e = base + (size_t)kk * 1024 + t * 4;
        if (e + 4 <= NE) {
            int4 d = *(const int4*)(dst + e);
            atomicAdd(&h[d.x >> 9], 1);
            atomicAdd(&h[d.y >> 9], 1);
            atomicAdd(&h[d.z >> 9], 1);
            atomicAdd(&h[d.w >> 9], 1);
        } else {
            for (int j = 0; j < 4; ++j)
                if (e + j < NE) atomicAdd(&h[dst[e + j] >> 9], 1);
        }
    }
    __syncthreads();
    int r = blockIdx.x & 7;
    for (int i = t; i < BKT; i += 256)
        if (h[i]) atomicAdd(&ghist[r * BKT + i], h[i]);
}

// ---------------- pass 2: scan 3128 counters ----------------
__global__ __launch_bounds__(1024) void scan_small_kernel(const int* __restrict__ ghist,
                                                          int* __restrict__ bbase, int* __restrict__ bcur) {
    __shared__ int c[1024];
    int t = threadIdx.x;
    int v[4];
    int sum = 0;
    #pragma unroll
    for (int j = 0; j < 4; ++j) {
        int idx = t * 4 + j;                 // logical order: idx = b*8 + r
        int x = 0;
        if (idx < NCTR) x = ghist[(idx & 7) * BKT + (idx >> 3)];
        v[j] = x; sum += x;
    }
    c[t] = sum;
    __syncthreads();
    for (int off = 1; off < 1024; off <<= 1) {
        int u = (t >= off) ? c[t - off] : 0;
        __syncthreads();
        c[t] += u;
        __syncthreads();
    }
    int run = (t == 0) ? 0 : c[t - 1];
    #pragma unroll
    for (int j = 0; j < 4; ++j) {
        int idx = t * 4 + j;
        if (idx < NCTR) {
            bbase[idx] = run;
            bcur[(idx & 7) * BKT + (idx >> 3)] = run;
        }
        run += v[j];
    }
    if (t == 1023) bbase[NCTR] = run;
}

// ---------------- pass 3: multisplit scatter ----------------
__global__ __launch_bounds__(256) void p2_kernel(const int* __restrict__ src, const int* __restrict__ dst,
                                                 int* __restrict__ bcur, unsigned int* __restrict__ packed) {
    __shared__ int h[BKT], gb[BKT], lc[BKT];
    int t = threadIdx.x;
    for (int i = t; i < BKT; i += 256) { h[i] = 0; lc[i] = 0; }
    __syncthreads();
    size_t base = (size_t)blockIdx.x * T2;
    for (int kk = 0; kk < 32; ++kk) {
        size_t e = base + (size_t)kk * 1024 + t * 4;
        if (e + 4 <= NE) {
            int4 d = *(const int4*)(dst + e);
            atomicAdd(&h[d.x >> 9], 1);
            atomicAdd(&h[d.y >> 9], 1);
            atomicAdd(&h[d.z >> 9], 1);
            atomicAdd(&h[d.w >> 9], 1);
        } else {
            for (int j = 0; j < 4; ++j)
                if (e + j < NE) atomicAdd(&h[dst[e + j] >> 9], 1);
        }
    }
    __syncthreads();
    int r = blockIdx.x & 7;
    for (int i = t; i < BKT; i += 256)
        gb[i] = h[i] ? atomicAdd(&bcur[r * BKT + i], h[i]) : 0;
    __syncthreads();
    for (int kk = 0; kk < 32; ++kk) {
        size_t e = base + (size_t)kk * 1024 + t * 4;
        if (e + 4 <= NE) {
            int4 d = *(const int4*)(dst + e);
            int4 s = *(const int4*)(src + e);
            int b, p;
            b = d.x >> 9; p = gb[b] + atomicAdd(&lc[b], 1); packed[p] = ((unsigned)s.x << 9) | (unsigned)(d.x & 511);
            b = d.y >> 9; p = gb[b] + atomicAdd(&lc[b], 1); packed[p] = ((unsigned)s.y << 9) | (unsigned)(d.y & 511);
            b = d.z >> 9; p = gb[b] + atomicAdd(&lc[b], 1); packed[p] = ((unsigned)s.z << 9) | (unsigned)(d.z & 511);
            b = d.w >> 9; p = gb[b] + atomicAdd(&lc[b], 1); packed[p] = ((unsigned)s.w << 9) | (unsigned)(d.w & 511);
        } else {
            for (int j = 0; j < 4; ++j) {
                if (e + j < NE) {
                    int dd = dst[e + j], ssv = src[e + j];
                    int b = dd >> 9;
                    int p = gb[b] + atomicAdd(&lc[b], 1);
                    packed[p] = ((unsigned)ssv << 9) | (unsigned)(dd & 511);
                }
            }
        }
    }
}

// ---------------- pass 4: per-bucket CSR finalize, segments ordered by (dst_low, src_slice) ----------------
__global__ __launch_bounds__(256) void p3_kernel(const unsigned int* __restrict__ packed, const int* __restrict__ bbase,
                                                 int* __restrict__ col, int* __restrict__ rowstart,
                                                 float* __restrict__ dinv) {
    __shared__ int lcnt[BNODE * NSLC], lexc[BNODE * NSLC], lcur[BNODE * NSLC];
    __shared__ int tmp[256];
    int t = threadIdx.x;
    int b = blockIdx.x;
    for (int i = t; i < BNODE * NSLC; i += 256) { lcnt[i] = 0; lcur[i] = 0; }
    __syncthreads();
    int beg = bbase[b * 8], end = bbase[(b + 1) * 8];
    for (int i = beg + t; i < end; i += 256) {
        unsigned p = packed[i];
        int k = (int)(p & 511) * NSLC + (int)(p >> 9) / SLCW;
        atomicAdd(&lcnt[k], 1);
    }
    __syncthreads();
    int myv[8];
    int ssum = 0;
    #pragma unroll
    for (int j = 0; j < 8; ++j) { myv[j] = lcnt[t * 8 + j]; ssum += myv[j]; }
    tmp[t] = ssum;
    __syncthreads();
    for (int off = 1; off < 256; off <<= 1) {
        int u = (t >= off) ? tmp[t - off] : 0;
        __syncthreads();
        tmp[t] += u;
        __syncthreads();
    }
    int run = (t == 0) ? 0 : tmp[t - 1];
    #pragma unroll
    for (int j = 0; j < 8; ++j) { lexc[t * 8 + j] = run; run += myv[j]; }
    __syncthreads();
    for (int i = beg + t; i < end; i += 256) {
        unsigned p = packed[i];
        int sv = (int)(p >> 9);
        int k = (int)(p & 511) * NSLC + sv / SLCW;
        int pos = lexc[k] + atomicAdd(&lcur[k], 1);
        col[beg + pos] = sv;
    }
    __syncthreads();
    int n0 = b * BNODE;
    for (int i = t; i < BNODE; i += 256) {
        int n = n0 + i;
        if (n < NN) {
            int st = lexc[i * NSLC];
            int en = (i == BNODE - 1) ? (end - beg) : lexc[(i + 1) * NSLC];
            rowstart[n] = beg + en;                       // exclusive row end
            dinv[n] = rsqrtf(1.0f + (float)(en - st));
        }
    }
}

// ---------------- layer0 linear: y_bf16 = (x @ W0) * dinv ----------------
__global__ __launch_bounds__(256) void lin0_kernel(const float* __restrict__ x, const float* __restrict__ W,
                                                   const float* __restrict__ dinv, ushort_t* __restrict__ yb) {
    __shared__ float sW[FIN * DIM];
    __shared__ float sX[64 * 65];
    __shared__ ushort_t sO[64 * 32];
    int tid = threadIdx.x;
    for (int i = tid; i < FIN * DIM; i += 256) sW[i] = W[i];
    int n0 = blockIdx.x * 64;
    #pragma unroll
    for (int k = 0; k < 16; ++k) {
        int idx = tid + k * 256;
        int row = idx >> 6, colf = idx & 63;
        sX[row * 65 + colf] = x[(size_t)(n0 + row) * FIN + colf];
    }
    __syncthreads();
    int nl = tid & 63, wq = tid >> 6;
    float acc[5] = {0.f, 0.f, 0.f, 0.f, 0.f};
    for (int f = 0; f < FIN; ++f) {
        float xv = sX[nl * 65 + f];
        #pragma unroll
        for (int k = 0; k < 5; ++k) acc[k] += xv * sW[f * DIM + wq + 4 * k];
    }
    float dv = dinv[n0 + nl];
    #pragma unroll
    for (int k = 0; k < 5; ++k) sO[nl * 32 + wq + 4 * k] = f2bf(acc[k] * dv);
    __syncthreads();
    if (tid < 192) {                                   // 64 rows x 3 uint4 (bytes 0..47)
        int row = tid / 3, part = tid - row * 3;
        ((uint4*)(yb + (size_t)(n0 + row) * 32))[part] = ((const uint4*)(sO + row * 32))[part];
    }
}

// ---------------- CSR gather: 2 lanes/node, forced 4-row MLP via inline-asm loads ----------------
__global__ __launch_bounds__(256) void gather_kernel(const ushort_t* __restrict__ yb, const int* __restrict__ col,
                                                     const int* __restrict__ rowstart, const float* __restrict__ dinv,
                                                     const float* __restrict__ bia, float* __restrict__ agg,
                                                     float* __restrict__ stats) {
    __shared__ float ls[2 * DIM];
    int tid = threadIdx.x;
    if (tid < 2 * DIM) ls[tid] = 0.f;
    __syncthreads();
    int n = blockIdx.x * 128 + (tid >> 1);
    int h = tid & 1;
    float acc[DIM];
    if (n < NN) {
        #pragma unroll
        for (int j = 0; j < DIM; ++j) acc[j] = 0.f;
        if (h == 0) row_acc(row_load(yb, n), acc);               // self-loop
        int beg = (n == 0) ? 0 : rowstart[n - 1];
        int end = rowstart[n];
        int e = beg + h;
        int cnt = (end - e + 1) >> 1;
        if (end <= e) cnt = 0;
        while (cnt >= 4) {                                       // 12 loads truly outstanding
            int s0 = col[e], s1 = col[e + 2], s2 = col[e + 4], s3 = col[e + 6];
            uint4 a0, b0, a1, b1, a2, b2, a3, b3;
            uint2 c0, c1, c2, c3;
            row_load_asm(yb, s0, a0, b0, c0);
            row_load_asm(yb, s1, a1, b1, c1);
            row_load_asm(yb, s2, a2, b2, c2);
            row_load_asm(yb, s3, a3, b3, c3);
            asm volatile("s_waitcnt vmcnt(0)" ::: "memory");
            __builtin_amdgcn_sched_barrier(0);
            acc10(a0, b0, c0, acc);
            acc10(a1, b1, c1, acc);
            acc10(a2, b2, c2, acc);
            acc10(a3, b3, c3, acc);
            e += 8; cnt -= 4;
        }
        if (cnt >= 2) {
            int s0 = col[e], s1 = col[e + 2];
            uint4 a0, b0, a1, b1;
            uint2 c0, c1;
            row_load_asm(yb, s0, a0, b0, c0);
            row_load_asm(yb, s1, a1, b1, c1);
            asm volatile("s_waitcnt vmcnt(0)" ::: "memory");
            __builtin_amdgcn_sched_barrier(0);
            acc10(a0, b0, c0, acc);
            acc10(a1, b1, c1, acc);
            e += 4; cnt -= 2;
        }
        if (cnt > 0) row_acc(row_load(yb, col[e]), acc);
        float di = dinv[n];
        #pragma unroll
        for (int j = 0; j < DIM; ++j) {
            acc[j] += __shfl_xor(acc[j], 1, 64);
            acc[j] = acc[j] * di + bia[j];
        }
        float* ar = agg + (size_t)n * DIM;
        if (h == 0) {
            *(float4*)(ar)     = make_float4(acc[0], acc[1], acc[2], acc[3]);
            *(float4*)(ar + 4) = make_float4(acc[4], acc[5], acc[6], acc[7]);
            *(float4*)(ar + 8) = make_float4(acc[8], acc[9], acc[10], acc[11]);
        } else {
            *(float4*)(ar + 12) = make_float4(acc[12], acc[13], acc[14], acc[15]);
            *(float4*)(ar + 16) = make_float4(acc[16], acc[17], acc[18], acc[19]);
        }
        int pr = tid >> 1;
        #pragma unroll
        for (int jo = 0; jo < 10; ++jo) {
            int j = ((jo + pr) % 10) + 10 * h;
            atomicAdd(&ls[j], acc[j]);
            atomicAdd(&ls[DIM + j], acc[j] * acc[j]);
        }
    }
    __syncthreads();
    if (tid < 2 * DIM) atomicAdd(&stats[tid], ls[tid]);
}

// ---------------- next linear (BN folded): y_bf16 = (relu(bn(agg)) @ W) * dinv ----------------
__global__ __launch_bounds__(256) void lin_next_kernel(const float* __restrict__ a, const float* __restrict__ stats,
                                                       const float* __restrict__ g, const float* __restrict__ beta,
                                                       const float* __restrict__ W, const float* __restrict__ dinv,
                                                       ushort_t* __restrict__ yb) {
    __shared__ float sW[DIM * DIM];
    __shared__ float sH[64 * 21];
    __shared__ float sS[2 * DIM];
    __shared__ ushort_t sO[64 * 32];
    int tid = threadIdx.x;
    for (int i = tid; i < DIM * DIM; i += 256) sW[i] = W[i];
    if (tid < DIM) {
        float mean = stats[tid] * (1.0f / NN);
        float var = stats[DIM + tid] * (1.0f / NN) - mean * mean;
        float sc = g[tid] * rsqrtf(var + BN_EPS);
        sS[tid] = sc;
        sS[DIM + tid] = beta[tid] - mean * sc;
    }
    __syncthreads();
    int n0 = blockIdx.x * 64;
    #pragma unroll
    for (int k = 0; k < 5; ++k) {
        int idx = tid + k * 256;
        int row = idx / DIM, colf = idx - row * DIM;
        float v = a[(size_t)(n0 + row) * DIM + colf];
        sH[row * 21 + colf] = fmaxf(v * sS[colf] + sS[DIM + colf], 0.0f);
    }
    __syncthreads();
    int nl = tid & 63, wq = tid >> 6;
    float acc[5] = {0.f, 0.f, 0.f, 0.f, 0.f};
    for (int f = 0; f < DIM; ++f) {
        float h = sH[nl * 21 + f];
        #pragma unroll
        for (int k = 0; k < 5; ++k) acc[k] += h * sW[f * DIM + wq + 4 * k];
    }
    float dv = dinv[n0 + nl];
    #pragma unroll
    for (int k = 0; k < 5; ++k) sO[nl * 32 + wq + 4 * k] = f2bf(acc[k] * dv);
    __syncthreads();
    if (tid < 192) {
        int row = tid / 3, part = tid - row * 3;
        ((uint4*)(yb + (size_t)(n0 + row) * 32))[part] = ((const uint4*)(sO + row * 32))[part];
    }
}

// ---------------- final (BN folded): relu(bn) -> emb + segment_max ----------------
__global__ __launch_bounds__(256) void final_kernel(const float* __restrict__ a, const float* __restrict__ stats,
                                                    const float* __restrict__ g, const float* __restrict__ beta,
                                                    const int* __restrict__ batch, float* __restrict__ emb,
                                                    unsigned int* __restrict__ ge) {
    __shared__ unsigned int lmax[8 * DIM];
    __shared__ float sS[2 * DIM];
    __shared__ int sg[2];
    int tid = threadIdx.x;
    if (tid < DIM) {
        float mean = stats[tid] * (1.0f / NN);
        float var = stats[DIM + tid] * (1.0f / NN) - mean * mean;
        float sc = g[tid] * rsqrtf(var + BN_EPS);
        sS[tid] = sc;
        sS[DIM + tid] = beta[tid] - mean * sc;
    }
    int n0 = blockIdx.x * 256;
    if (tid == 0) {
        int nlast = min(n0 + 255, NN - 1);
        sg[0] = batch[n0];
        sg[1] = batch[nlast] - batch[n0] + 1;
    }
    for (int i = tid; i < 8 * DIM; i += 256) lmax[i] = 0u;
    __syncthreads();
    int gmin = sg[0], gspan = sg[1];
    bool uselds = (gspan <= 8);
    int n = n0 + tid;
    if (n < NN) {
        int g2 = batch[n];
        float vals[DIM];
        const float4* ar = (const float4*)(a + (size_t)n * DIM);
        float4* er = (float4*)(emb + (size_t)n * DIM);
        #pragma unroll
        for (int c = 0; c < 5; ++c) {
            float4 v = ar[c];
            float r0 = fmaxf(v.x * sS[4*c+0] + sS[DIM + 4*c+0], 0.0f);
            float r1 = fmaxf(v.y * sS[4*c+1] + sS[DIM + 4*c+1], 0.0f);
            float r2 = fmaxf(v.z * sS[4*c+2] + sS[DIM + 4*c+2], 0.0f);
            float r3 = fmaxf(v.w * sS[4*c+3] + sS[DIM + 4*c+3], 0.0f);
            er[c] = make_float4(r0, r1, r2, r3);
            vals[4*c+0] = r0; vals[4*c+1] = r1; vals[4*c+2] = r2; vals[4*c+3] = r3;
        }
        if (uselds) {
            int base = (g2 - gmin) * DIM;
            #pragma unroll
            for (int jo = 0; jo < DIM; ++jo) {
                int j = (jo + tid) % DIM;
                atomicMax(&lmax[base + j], __float_as_uint(vals[j]));
            }
        } else {
            #pragma unroll
            for (int jo = 0; jo < DIM; ++jo) {
                int j = (jo + tid) % DIM;
                atomicMax(&ge[g2 * DIM + j], __float_as_uint(vals[j]));
            }
        }
    }
    __syncthreads();
    if (uselds) {
        for (int i = tid; i < gspan * DIM; i += 256) {
            unsigned int v = lmax[i];
            if (v) atomicMax(&ge[gmin * DIM + i], v);
        }
    }
}

// ---------------- fc head ----------------
__global__ __launch_bounds__(256) void fc_kernel(const float* __restrict__ ge, const float* __restrict__ fcW,
                                                 const float* __restrict__ fcb, float* __restrict__ out) {
    int gid = blockIdx.x * 256 + threadIdx.x;
    if (gid >= NGR * NCL) return;
    int g = gid >> 1, c = gid & 1;
    float acc = fcb[c];
    #pragma unroll
    for (int d = 0; d < DIM; ++d) acc += ge[g * DIM + d] * fcW[d * NCL + c];
    out[gid] = acc;
}

extern "C" void kernel_launch(void* const* d_in, const int* in_sizes, int n_in,
                              void* d_out, int out_size, void* d_ws, size_t ws_size,
                              hipStream_t stream) {
    const float* x     = (const float*)d_in[0];
    const int*   ei    = (const int*)d_in[1];
    const int*   src   = ei;
    const int*   dst   = ei + NE;
    const int*   batch = (const int*)d_in[2];
    const float* W0 = (const float*)d_in[3];  const float* b0 = (const float*)d_in[4];
    const float* g0 = (const float*)d_in[5];  const float* be0 = (const float*)d_in[6];
    const float* W1 = (const float*)d_in[7];  const float* b1 = (const float*)d_in[8];
    const float* g1 = (const float*)d_in[9];  const float* be1 = (const float*)d_in[10];
    const float* W2 = (const float*)d_in[11]; const float* b2 = (const float*)d_in[12];
    const float* g2 = (const float*)d_in[13]; const float* be2 = (const float*)d_in[14];
    const float* fcW = (const float*)d_in[15]; const float* fcb = (const float*)d_in[16];

    float* ws = (float*)d_ws;
    float* dinv     = ws;                               // NN
    int*   rowstart = (int*)(ws + NN);                  // NN (exclusive row ends)
    float* stats    = ws + 2 * NN;                      // 192
    int*   ghist    = (int*)(stats + 192);              // NCTR
    int*   bbase    = ghist + NCTR;                     // NCTR+1
    int*   bcur     = bbase + NCTR + 1;                 // NCTR
    float* agg      = ws + 409700;                      // NN*DIM fp32; aliases packed[]
    unsigned int* packed = (unsigned int*)agg;          // NE u32 == NN*DIM
    ushort_t* ybuf  = (ushort_t*)(ws + 4409712);        // NN rows x 64B
    int*   col      = (int*)(ws + 4409712 + (size_t)NN * 16);   // NE ints

    float* emb    = (float*)d_out;                      // NN*DIM
    float* ge     = emb + (size_t)NN * DIM;             // NGR*DIM
    float* logits = ge + NGR * DIM;                     // NGR*NCL

    const int N_BLKS = (NN + 255) / 256;                // 782
    const int L_BLKS = NN / 64;                         // 3125 (linears)
    const int G_BLKS = (NN + 127) / 128;                // 1563 (gather)

    hipMemsetAsync(ghist, 0, NCTR * sizeof(int), stream);
    hipMemsetAsync(stats, 0, 192 * sizeof(float), stream);
    hipMemsetAsync(ge, 0, NGR * DIM * sizeof(float), stream);

    // ---- CSR build: two-level multisplit, (dst_low, src_slice)-sorted segments ----
    hist_kernel<<<NT2, 256, 0, stream>>>(dst, ghist);
    scan_small_kernel<<<1, 1024, 0, stream>>>(ghist, bbase, bcur);
    p2_kernel<<<NT2, 256, 0, stream>>>(src, dst, bcur, packed);
    p3_kernel<<<BKT, 256, 0, stream>>>(packed, bbase, col, rowstart, dinv);

    lin0_kernel<<<L_BLKS, 256, 0, stream>>>(x, W0, dinv, ybuf);   // packed dead after p3

    gather_kernel<<<G_BLKS, 256, 0, stream>>>(ybuf, col, rowstart, dinv, b0, agg, stats);
    lin_next_kernel<<<L_BLKS, 256, 0, stream>>>(agg, stats, g0, be0, W1, dinv, ybuf);

    gather_kernel<<<G_BLKS, 256, 0, stream>>>(ybuf, col, rowstart, dinv, b1, agg, stats + 64);
    lin_next_kernel<<<L_BLKS, 256, 0, stream>>>(agg, stats + 64, g1, be1, W2, dinv, ybuf);

    gather_kernel<<<G_BLKS, 256, 0, stream>>>(ybuf, col, rowstart, dinv, b2, agg, stats + 128);

    final_kernel<<<N_BLKS, 256, 0, stream>>>(agg, stats + 128, g2, be2, batch, emb, (unsigned int*)ge);
    fc_kernel<<<(NGR * NCL + 255) / 256, 256, 0, stream>>>(ge, fcW, fcb, logits);
}